// Round 6
// baseline (2068.860 us; speedup 1.0000x reference)
//
#include <hip/hip_runtime.h>
#include <hip/hip_bf16.h>
#include <stdint.h>

#define N_TOKEN 16384
#define N_EMBED 512
#define QBLK 32
#define KVB 32
#define NT (N_TOKEN / KVB)   // 512 tiles

typedef __attribute__((ext_vector_type(8))) short bf16x8;
typedef __attribute__((ext_vector_type(4))) float f32x4;

__device__ __forceinline__ unsigned short f2bf(float f) {
  unsigned u = __float_as_uint(f);
  u = (u + 0x7FFFu + ((u >> 16) & 1u)) >> 16;
  return (unsigned short)u;
}
__device__ __forceinline__ float bfhi2f(unsigned u) {  // high 16 bits as bf16
  return __uint_as_float(u & 0xFFFF0000u);
}
__device__ __forceinline__ float bflo2f(unsigned u) {  // low 16 bits as bf16
  return __uint_as_float(u << 16);
}
__device__ __forceinline__ unsigned pk2(float a, float b) {
  float2 f;
  f.x = a;
  f.y = b;
  __hip_bfloat162 h = __float22bfloat162_rn(f);
  unsigned u;
  __builtin_memcpy(&u, &h, 4);
  return u;
}

__device__ __forceinline__ void load_lds16(const void* g, void* l) {
  __builtin_amdgcn_global_load_lds((const __attribute__((address_space(1))) void*)g,
                                   (__attribute__((address_space(3))) void*)l, 16, 0, 0);
}

// ---------------- prep: f32 -> bf16 (8 elems/thread) ----------------
__global__ void cvt_bf16_kernel(const float* __restrict__ in, unsigned short* __restrict__ out, int n8) {
  int i = blockIdx.x * blockDim.x + threadIdx.x;
  if (i >= n8) return;
  float4 a = ((const float4*)in)[i * 2 + 0];
  float4 b = ((const float4*)in)[i * 2 + 1];
  uint4 o;
  o.x = (unsigned)f2bf(a.x) | ((unsigned)f2bf(a.y) << 16);
  o.y = (unsigned)f2bf(a.z) | ((unsigned)f2bf(a.w) << 16);
  o.z = (unsigned)f2bf(b.x) | ((unsigned)f2bf(b.y) << 16);
  o.w = (unsigned)f2bf(b.z) | ((unsigned)f2bf(b.w) << 16);
  ((uint4*)out)[i] = o;
}

// ---------------- prep: value_w [N][E] f32 -> vt [E][N] bf16 ----------------
__global__ void transpose_cvt_kernel(const float* __restrict__ in, unsigned short* __restrict__ out) {
  __shared__ float tile[64][65];
  int n0 = blockIdx.x * 64;
  int e0 = blockIdx.y * 64;
  int c = threadIdx.x & 63;
  int r0 = threadIdx.x >> 6;
#pragma unroll
  for (int r = r0; r < 64; r += 4)
    tile[r][c] = in[(size_t)(n0 + r) * N_EMBED + e0 + c];
  __syncthreads();
#pragma unroll
  for (int r = r0; r < 64; r += 4)
    out[(size_t)(e0 + r) * N_TOKEN + n0 + c] = f2bf(tile[c][r]);
}

// ---------------- main fused flash kernel ----------------
// 512 blocks x 512 threads (8 waves), 2 blocks/CU. Block = 32 q-rows, sweeps
// ALL kv in the same tile order (L2-synchronized sharing across all blocks).
// Pipeline per region (ONE barrier): QK(t) || exp(t-1) || PV(t-2) || stage(t+1).
// QK (swapped, S^T = K*Q^T): wave (we=w&1: E-256, wn=(w>>1)&1: kv-16, wq=w>>2: q-16).
// exp: thread (q=tid>>4, kvpair=tid&15). PV (swapped, O^T = V^T*P^T): wave w
// owns e-slice [64w, 64w+64).
__global__ __launch_bounds__(512, 4) void flash5_kernel(
    const unsigned short* __restrict__ xb,   // [T][512] bf16
    const unsigned short* __restrict__ kb,   // [N][512] bf16 (lin_w)
    const unsigned short* __restrict__ vt,   // [512][N] bf16 (value_w^T)
    const float* __restrict__ bias,          // [N]
    const float* __restrict__ xf,            // [T][512] f32 (residual)
    float* __restrict__ out)                 // [T][512] f32
{
  // K: 2 x 32KB (row-swizzled). Sp: [2 buf][2 we][32 q][72B]. Pb: [2 buf][32 q][80B].
  __shared__ __align__(16) unsigned char lds[65536 + 9216 + 5120 + 128];
  unsigned char* Ks = lds;
  unsigned char* Sp = lds + 65536;
  unsigned char* Pb = lds + 65536 + 9216;
  float* lsumB = (float*)(lds + 65536 + 9216 + 5120);

  const int tid = threadIdx.x;
  const int w = tid >> 6;
  const int lane = tid & 63;
  const int g = lane >> 4;
  const int l15 = lane & 15;
  const int we = w & 1, wn = (w >> 1) & 1, wq = w >> 2;
  const int qbase = blockIdx.x * QBLK;

  // exp-phase mapping
  const int eq = tid >> 4;   // q row 0..31
  const int ekp = tid & 15;  // kv pair 0..15

  // Q fragments (B-operand): rows qbase+16wq+l15, E = 256we + 32kk + 8g
  bf16x8 q[8];
#pragma unroll
  for (int kk = 0; kk < 8; ++kk)
    q[kk] = *(const bf16x8*)(xb + (size_t)(qbase + 16 * wq + l15) * N_EMBED + 256 * we + 32 * kk + 8 * g);

  const f32x4 fzero = {0.f, 0.f, 0.f, 0.f};
  f32x4 acc[2][4];  // O^T: [rf: q-16 halves][cf: e-16 within wave's 64]
#pragma unroll
  for (int rf = 0; rf < 2; ++rf)
#pragma unroll
    for (int cf = 0; cf < 4; ++cf) acc[rf][cf] = fzero;
  float lsum_reg = 0.f;

  // precomputed byte offsets
  // Sp write: q-row = 16*wq + l15 (FIX: wq term was missing in R5 -> NaN)
  const int spw_off = we * 2304 + (16 * wq + l15) * 72 + 32 * wn + 8 * g;  // b64 write
  const int spr_off = eq * 72 + ekp * 4;                       // Sp read (b32, per we-plane)
  const int pbw_off = eq * 80 + ekp * 4;                       // Pb write (b32)
  const int pbr0 = l15 * 80 + 16 * g;                          // Pb read rf=0 (b128)
  const int pbr1 = (16 + l15) * 80 + 16 * g;                   // Pb read rf=1
  const int krow = 16 * wn + l15;

  auto stage = [&](int half, int t) {
    const unsigned char* kg = (const unsigned char*)(kb + (size_t)t * KVB * N_EMBED);
    unsigned char* Kd = Ks + half * 32768;
#pragma unroll
    for (int it = 0; it < 4; ++it) {
      int c = tid + 512 * it;   // 2048 chunks of 16B
      int row = c >> 6;         // 64 chunks per 1024B row
      int cb = (c & 63) * 16;
      load_lds16(kg + row * 1024 + (cb ^ ((row & 7) << 4)), Kd + c * 16);
    }
  };

  stage(0, 0);

  for (int t = 0; t < NT + 2; ++t) {
    asm volatile("s_waitcnt vmcnt(0) lgkmcnt(0)" ::: "memory");
    __builtin_amdgcn_sched_barrier(0);
    __builtin_amdgcn_s_barrier();

    // ---- hoisted LDS reads (previous regions' buffers; latency hides under QK)
    unsigned su0 = 0, su1 = 0;
    if (t >= 1 && t <= NT) {
      const unsigned char* sp = Sp + ((t - 1) & 1) * 4608 + spr_off;
      su0 = *(const unsigned*)(sp);
      su1 = *(const unsigned*)(sp + 2304);
    }
    bf16x8 pb0 = {}, pb1 = {};
    bf16x8 bv[4];
    if (t >= 2) {
      const unsigned char* pb = Pb + (t & 1) * 2560;
      pb0 = *(const bf16x8*)(pb + pbr0);
      pb1 = *(const bf16x8*)(pb + pbr1);
      // V A-fragments direct from global (L2): row e = 64w+16cf+l15, kv = (t-2)*32+8g
      const unsigned short* vbase = vt + (size_t)(64 * w + l15) * N_TOKEN + (t - 2) * KVB + 8 * g;
#pragma unroll
      for (int cf = 0; cf < 4; ++cf)
        bv[cf] = *(const bf16x8*)(vbase + (size_t)(16 * cf) * N_TOKEN);
    }
    float2 bb = {0.f, 0.f};
    if (t >= 1 && t <= NT) bb = *(const float2*)(bias + (t - 1) * KVB + 2 * ekp);

    // ---- issue stage of K(t+1)
    if (t + 1 < NT) stage((t + 1) & 1, t + 1);

    // ---- QK(t): S^T[kv 16wn..+16][q 16wq..+16] over E-slice [256we,+256)
    if (t < NT) {
      const unsigned char* Kb = Ks + (t & 1) * 32768 + krow * 1024;
      f32x4 c0 = fzero, c1 = fzero;
      __builtin_amdgcn_s_setprio(1);
#pragma unroll
      for (int kk = 0; kk < 4; ++kk) {
        int cb0 = 512 * we + 64 * kk + 16 * g;
        int cb1 = cb0 + 256;
        bf16x8 bk0 = *(const bf16x8*)(Kb + (cb0 ^ ((krow & 7) << 4)));
        bf16x8 bk1 = *(const bf16x8*)(Kb + (cb1 ^ ((krow & 7) << 4)));
        c0 = __builtin_amdgcn_mfma_f32_16x16x32_bf16(bk0, q[kk], c0, 0, 0, 0);
        c1 = __builtin_amdgcn_mfma_f32_16x16x32_bf16(bk1, q[kk + 4], c1, 0, 0, 0);
      }
      __builtin_amdgcn_s_setprio(0);
      f32x4 c = c0 + c1;
      uint2 wv;
      wv.x = pk2(c[0], c[1]);
      wv.y = pk2(c[2], c[3]);
      *(uint2*)(Sp + (t & 1) * 4608 + spw_off) = wv;
    }

    // ---- exp(t-1): combine E-halves + bias, exp, write P to Pb[(t-1)&1]
    if (t >= 1 && t <= NT) {
      float lo = bflo2f(su0) + bflo2f(su1) + bb.x;
      float hi = bfhi2f(su0) + bfhi2f(su1) + bb.y;
      float e0 = exp2f(lo * 1.44269504f);
      float e1 = exp2f(hi * 1.44269504f);
      lsum_reg += e0 + e1;
      *(unsigned*)(Pb + ((t - 1) & 1) * 2560 + pbw_off) = pk2(e0, e1);
    }

    // ---- PV(t-2): O^T[e 64w..+64][q 32] += V^T * P^T
    if (t >= 2) {
      __builtin_amdgcn_s_setprio(1);
#pragma unroll
      for (int cf = 0; cf < 4; ++cf) {
        acc[0][cf] = __builtin_amdgcn_mfma_f32_16x16x32_bf16(bv[cf], pb0, acc[0][cf], 0, 0, 0);
        acc[1][cf] = __builtin_amdgcn_mfma_f32_16x16x32_bf16(bv[cf], pb1, acc[1][cf], 0, 0, 0);
      }
      __builtin_amdgcn_s_setprio(0);
    }
  }

  // ---- epilogue: reduce lsum over the 16 kv-pair lanes of each q-row
  {
    float r = lsum_reg;
    r += __shfl_xor(r, 1, 64);
    r += __shfl_xor(r, 2, 64);
    r += __shfl_xor(r, 4, 64);
    r += __shfl_xor(r, 8, 64);
    if (ekp == 0) lsumB[eq] = r;
  }
  __syncthreads();

  // O^T frag: lane (l15,g) holds q = 16rf+l15 (col), e = 64w+16cf+4g+j (row)
#pragma unroll
  for (int rf = 0; rf < 2; ++rf) {
    float inv = 1.0f / lsumB[16 * rf + l15];
    int row = qbase + 16 * rf + l15;
#pragma unroll
    for (int cf = 0; cf < 4; ++cf)
#pragma unroll
      for (int j = 0; j < 4; ++j) {
        int col = 64 * w + 16 * cf + 4 * g + j;
        size_t idx = (size_t)row * N_EMBED + col;
        out[idx] = acc[rf][cf][j] * inv + xf[idx];
      }
  }
}

extern "C" void kernel_launch(void* const* d_in, const int* in_sizes, int n_in,
                              void* d_out, int out_size, void* d_ws, size_t ws_size,
                              hipStream_t stream) {
  const float* x = (const float*)d_in[0];        // [8,2048,512] f32
  const float* lin_w = (const float*)d_in[1];    // [16384,512] f32
  const float* lin_b = (const float*)d_in[2];    // [16384] f32
  const float* value_w = (const float*)d_in[3];  // [16384,512] f32
  float* outp = (float*)d_out;

  unsigned short* xb = (unsigned short*)d_ws;                        // 16MB
  unsigned short* wb = (unsigned short*)((char*)d_ws + (16 << 20));  // 16MB
  unsigned short* vt = (unsigned short*)((char*)d_ws + (32 << 20));  // 16MB

  const int n8 = (N_TOKEN * N_EMBED) / 8;  // 1048576
  cvt_bf16_kernel<<<n8 / 256, 256, 0, stream>>>(x, xb, n8);
  cvt_bf16_kernel<<<n8 / 256, 256, 0, stream>>>(lin_w, wb, n8);
  transpose_cvt_kernel<<<dim3(N_TOKEN / 64, N_EMBED / 64), 256, 0, stream>>>(value_w, vt);
  flash5_kernel<<<N_TOKEN / QBLK, 512, 0, stream>>>(xb, wb, vt, lin_b, x, outp);
}